// Round 9
// baseline (35.020 us; speedup 1.0000x reference)
//
#include <hip/hip_runtime.h>
#include <hip/hip_bf16.h>
#include <hip/hip_cooperative_groups.h>

namespace cg = cooperative_groups;

#define Bq 2
#define Sq 2048
#define Hq 16
#define CHUNK 64
#define NC 32
#define UNITS 4   // chunks per block in the fused kernel (grid = 1024/UNITS)

typedef __attribute__((ext_vector_type(8))) short short8;  // 8 bf16
typedef __attribute__((ext_vector_type(4))) float f32x4;
typedef unsigned short ushort_t;
typedef unsigned int uint_t;

__device__ inline short f2b(float f) {
  __hip_bfloat16 h = __float2bfloat16(f);
  return *reinterpret_cast<short*>(&h);
}

// XOR-swizzled element index for a 64x64 bf16 tile (128B rows, 16B slots).
__device__ inline int swz(int row, int col) {
  return (row << 6) + ((((col >> 3) ^ (row & 7))) << 3) + (col & 7);
}

// ===========================================================================
// FUSED cooperative kernel: Phase A (KV chunk sums; K^T/V^T stay in LDS) ->
// grid sync -> Phase B (chunk-prefix scan of M in ws) -> grid sync ->
// Phase C (O = gate * (mask(QK^T)V + Q M_prev)).
// 256 blocks x 256 threads, 4 chunks/block; 72KB LDS -> 2 blocks/CU capacity,
// so 256 co-resident blocks have 2x headroom.
// ===========================================================================
__global__ __launch_bounds__(256, 2) void fused_attn_kernel(
    const float* __restrict__ qk, const float* __restrict__ v,
    const float* __restrict__ nrm, ushort_t* __restrict__ wsM,
    float* __restrict__ out) {
  __shared__ short ktS[UNITS][4096];   // K^T[dk][s], swizzled
  __shared__ short vtS[UNITS][4096];   // V^T[dv][s], swizzled
  __shared__ short smS[4096];          // score bounce (per-wave rows)

  const int tid = threadIdx.x;
  const int w = tid >> 6, lane = tid & 63, g = lane >> 4, r16 = lane & 15;

  // ================= Phase A =================
  {
    const int x = tid & 63, seg = tid >> 6;
#pragma unroll
    for (int q = 0; q < UNITS; ++q) {
      const int u = blockIdx.x * UNITS + q;
      const int c = u & 31, h = (u >> 5) & 15, b = u >> 9;
      const int t0 = c * CHUNK;
      for (int e = 0; e < 2; ++e) {
        const int s0 = seg * 16 + e * 8;
        short8 kb, vb;
#pragma unroll
        for (int j = 0; j < 8; ++j) {
          const size_t t = (size_t)(b * Sq + t0 + s0 + j);
          kb[j] = f2b(qk[((t * 2 + 1) * Hq + h) * 64 + x]);  // coalesced col read
          vb[j] = f2b(v[(t * Hq + h) * 64 + x]);
        }
        *(short8*)&ktS[q][swz(x, s0)] = kb;
        *(short8*)&vtS[q][swz(x, s0)] = vb;
      }
    }
    __syncthreads();
#pragma unroll
    for (int q = 0; q < UNITS; ++q) {
      const int u = blockIdx.x * UNITS + q;
      short8 vf[2];
#pragma unroll
      for (int kk = 0; kk < 2; ++kk)
        vf[kk] = *(const short8*)&vtS[q][swz(16 * w + r16, kk * 32 + 8 * g)];
      ushort_t* dst = wsM + ((size_t)u << 12);
#pragma unroll
      for (int j = 0; j < 4; ++j) {
        f32x4 acc = {0.f, 0.f, 0.f, 0.f};
#pragma unroll
        for (int kk = 0; kk < 2; ++kk) {
          short8 kf = *(const short8*)&ktS[q][swz(16 * j + r16, kk * 32 + 8 * g)];
          acc = __builtin_amdgcn_mfma_f32_16x16x32_bf16(vf[kk], kf, acc, 0, 0, 0);
        }
#pragma unroll
        for (int reg = 0; reg < 4; ++reg)
          dst[(16 * w + 4 * g + reg) * 64 + 16 * j + r16] =
              (ushort_t)f2b(acc[reg]);
      }
    }
  }
  __threadfence();
  cg::this_grid().sync();

  // ================= Phase B: exclusive chunk-prefix scan of M ============
  {
    const int gi = blockIdx.x * 256 + tid;   // 65536 threads exactly
    if (gi < Bq * Hq * 2048) {
      const int bh = gi >> 11, e = gi & 2047;
      uint_t* p = (uint_t*)wsM + (size_t)bh * NC * 2048 + e;
      uint_t xv[NC];
#pragma unroll
      for (int cc = 0; cc < NC; ++cc) xv[cc] = p[cc * 2048];
      float r0 = 0.f, r1 = 0.f;
#pragma unroll
      for (int cc = 0; cc < NC; ++cc) {
        float lo = __uint_as_float(xv[cc] << 16);
        float hi = __uint_as_float(xv[cc] & 0xffff0000u);
        p[cc * 2048] =
            ((uint_t)(ushort_t)f2b(r1) << 16) | (uint_t)(ushort_t)f2b(r0);
        r0 += lo;
        r1 += hi;
      }
    }
  }
  __threadfence();
  cg::this_grid().sync();

  // ================= Phase C =================
#pragma unroll 1
  for (int q = 0; q < UNITS; ++q) {
    const int u = blockIdx.x * UNITS + q;
    const int c = u & 31, h = (u >> 5) & 15, b = u >> 9;
    const int t0 = c * CHUNK;
    const ushort_t* mm = wsM + ((size_t)u << 12);
    const int nk = (w >> 1) + 1;   // live s-tiles per wave: 1,1,2,2

    // ---- issue all global loads for this unit ----
    short8 mfr[4][2];
#pragma unroll
    for (int j = 0; j < 4; ++j)
#pragma unroll
      for (int kk = 0; kk < 2; ++kk)
        mfr[j][kk] =
            *(const short8*)(mm + (16 * j + r16) * 64 + kk * 32 + 8 * g);

    float4 kraw[4][4];   // K rows 16j+r16, fp32 (round-6-verified layout)
#pragma unroll
    for (int j = 0; j < 4; ++j) {
      const size_t s = (size_t)(b * Sq + t0 + 16 * j + r16);
      const float4* kp = (const float4*)(qk + ((s * 2 + 1) * Hq + h) * 64);
#pragma unroll
      for (int p2 = 0; p2 < 2; ++p2) {
        if (j <= w) {
          kraw[j][2 * p2]     = kp[8 * p2 + 2 * g];
          kraw[j][2 * p2 + 1] = kp[8 * p2 + 2 * g + 1];
        } else {
          kraw[j][2 * p2]     = make_float4(0.f, 0.f, 0.f, 0.f);
          kraw[j][2 * p2 + 1] = make_float4(0.f, 0.f, 0.f, 0.f);
        }
      }
    }

    float4 qraw[4];
    {
      const size_t t = (size_t)(b * Sq + t0 + 16 * w + r16);
      const float4* qp = (const float4*)(qk + ((t * 2 + 0) * Hq + h) * 64);
#pragma unroll
      for (int p2 = 0; p2 < 2; ++p2) {
        qraw[2 * p2]     = qp[8 * p2 + 2 * g];
        qraw[2 * p2 + 1] = qp[8 * p2 + 2 * g + 1];
      }
    }

    float gn[4];
#pragma unroll
    for (int reg = 0; reg < 4; ++reg)
      gn[reg] = nrm[((size_t)(b * Sq) + t0 + 16 * w + 4 * g + reg) * Hq + h];

    __builtin_amdgcn_sched_barrier(0);   // pin loads above compute

    short8 qf[2];
#pragma unroll
    for (int kk = 0; kk < 2; ++kk) {
      float4 a = qraw[2 * kk], bb = qraw[2 * kk + 1];
      short8 qv;
      qv[0] = f2b(a.x);  qv[1] = f2b(a.y);  qv[2] = f2b(a.z);  qv[3] = f2b(a.w);
      qv[4] = f2b(bb.x); qv[5] = f2b(bb.y); qv[6] = f2b(bb.z); qv[7] = f2b(bb.w);
      qf[kk] = qv;
    }

#pragma unroll
    for (int j = 0; j < 4; ++j) {
      f32x4 acc = {0.f, 0.f, 0.f, 0.f};
#pragma unroll
      for (int kk = 0; kk < 2; ++kk) {
        float4 a = kraw[j][2 * kk], bb = kraw[j][2 * kk + 1];
        short8 kf;
        kf[0] = f2b(a.x);  kf[1] = f2b(a.y);  kf[2] = f2b(a.z);  kf[3] = f2b(a.w);
        kf[4] = f2b(bb.x); kf[5] = f2b(bb.y); kf[6] = f2b(bb.z); kf[7] = f2b(bb.w);
        acc = __builtin_amdgcn_mfma_f32_16x16x32_bf16(qf[kk], kf, acc, 0, 0, 0);
      }
      const int scol = 16 * j + r16;
#pragma unroll
      for (int reg = 0; reg < 4; ++reg) {
        const int trow = 16 * w + 4 * g + reg;
        smS[swz(trow, scol)] = (scol <= trow) ? f2b(acc[reg]) : (short)0;
      }
    }
    asm volatile("s_waitcnt lgkmcnt(0)" ::: "memory");
    __builtin_amdgcn_sched_barrier(0);

    short8 sf0 = *(const short8*)&smS[swz(16 * w + r16, 8 * g)];
    short8 sf1 = short8{};
    if (nk > 1)
      sf1 = *(const short8*)&smS[swz(16 * w + r16, 32 + 8 * g)];

    float gr[4];
#pragma unroll
    for (int reg = 0; reg < 4; ++reg) gr[reg] = __expf(-gn[reg]);

#pragma unroll
    for (int j = 0; j < 4; ++j) {
      f32x4 acc = {0.f, 0.f, 0.f, 0.f};
      short8 vf0 = *(const short8*)&vtS[q][swz(16 * j + r16, 8 * g)];
      short8 vf1 = *(const short8*)&vtS[q][swz(16 * j + r16, 32 + 8 * g)];
      if (nk < 2) vf1 = short8{};
      acc = __builtin_amdgcn_mfma_f32_16x16x32_bf16(sf0, vf0, acc, 0, 0, 0);
      acc = __builtin_amdgcn_mfma_f32_16x16x32_bf16(sf1, vf1, acc, 0, 0, 0);
      acc = __builtin_amdgcn_mfma_f32_16x16x32_bf16(qf[0], mfr[j][0], acc, 0, 0, 0);
      acc = __builtin_amdgcn_mfma_f32_16x16x32_bf16(qf[1], mfr[j][1], acc, 0, 0, 0);
      const int dvv = 16 * j + r16;
#pragma unroll
      for (int reg = 0; reg < 4; ++reg) {
        const int trow = 16 * w + 4 * g + reg;
        out[((size_t)(b * Sq + t0 + trow) * Hq + h) * 64 + dvv] =
            gr[reg] * acc[reg];
      }
    }
  }
}

// ===========================================================================
// FALLBACK: round-6-verified 3-kernel path (34.7 us).
// ===========================================================================
__global__ __launch_bounds__(256) void kv_chunk_kernel(
    const float* __restrict__ qk, const float* __restrict__ v,
    ushort_t* __restrict__ wsM, ushort_t* __restrict__ wsV) {
  const int u = blockIdx.x;
  const int c = u & 31, h = (u >> 5) & 15, b = u >> 9;
  const int t0 = c * CHUNK;
  const int tid = threadIdx.x;
  __shared__ short ktS[4096];
  __shared__ short vtS[4096];

  const int x = tid & 63, seg = tid >> 6;
  for (int e = 0; e < 2; ++e) {
    const int s0 = seg * 16 + e * 8;
    short8 kb, vb;
#pragma unroll
    for (int j = 0; j < 8; ++j) {
      const size_t t = (size_t)(b * Sq + t0 + s0 + j);
      kb[j] = f2b(qk[((t * 2 + 1) * Hq + h) * 64 + x]);
      vb[j] = f2b(v[(t * Hq + h) * 64 + x]);
    }
    *(short8*)&ktS[swz(x, s0)] = kb;
    *(short8*)&vtS[swz(x, s0)] = vb;
  }
  __syncthreads();

  const int w = tid >> 6, lane = tid & 63, g = lane >> 4, r16 = lane & 15;
  short8 vf[2];
#pragma unroll
  for (int kk = 0; kk < 2; ++kk)
    vf[kk] = *(const short8*)&vtS[swz(16 * w + r16, kk * 32 + 8 * g)];

  {
    ushort_t* dvp = wsV + ((size_t)u << 12);
    short8 a0 = *(const short8*)&vtS[tid * 16];
    short8 a1 = *(const short8*)&vtS[tid * 16 + 8];
    *(short8*)(dvp + tid * 16) = a0;
    *(short8*)(dvp + tid * 16 + 8) = a1;
  }

  ushort_t* dst = wsM + ((size_t)u << 12);
#pragma unroll
  for (int j = 0; j < 4; ++j) {
    f32x4 acc = {0.f, 0.f, 0.f, 0.f};
#pragma unroll
    for (int kk = 0; kk < 2; ++kk) {
      short8 kf = *(const short8*)&ktS[swz(16 * j + r16, kk * 32 + 8 * g)];
      acc = __builtin_amdgcn_mfma_f32_16x16x32_bf16(vf[kk], kf, acc, 0, 0, 0);
    }
#pragma unroll
    for (int reg = 0; reg < 4; ++reg)
      dst[(16 * w + 4 * g + reg) * 64 + 16 * j + r16] = (ushort_t)f2b(acc[reg]);
  }
}

__global__ __launch_bounds__(256) void kv_scan_kernel(uint_t* __restrict__ kvw) {
  const int gi = blockIdx.x * 256 + threadIdx.x;
  const int bh = gi >> 11, e = gi & 2047;
  uint_t* p = kvw + (size_t)bh * NC * 2048 + e;
  uint_t xv[NC];
#pragma unroll
  for (int cc = 0; cc < NC; ++cc) xv[cc] = p[cc * 2048];
  float r0 = 0.f, r1 = 0.f;
#pragma unroll
  for (int cc = 0; cc < NC; ++cc) {
    float lo = __uint_as_float(xv[cc] << 16);
    float hi = __uint_as_float(xv[cc] & 0xffff0000u);
    p[cc * 2048] = ((uint_t)(ushort_t)f2b(r1) << 16) | (uint_t)(ushort_t)f2b(r0);
    r0 += lo;
    r1 += hi;
  }
}

__global__ __launch_bounds__(256) void attn_out_kernel(
    const float* __restrict__ qk, const float* __restrict__ nrm,
    const ushort_t* __restrict__ wsM, const ushort_t* __restrict__ wsV,
    float* __restrict__ out) {
  const int u = blockIdx.x;
  const int c = u & 31, h = (u >> 5) & 15, b = u >> 9;
  const int t0 = c * CHUNK;
  const int tid = threadIdx.x;
  const int w = tid >> 6, lane = tid & 63, g = lane >> 4, r16 = lane & 15;
  __shared__ short smS[4096];

  const ushort_t* mm = wsM + ((size_t)u << 12);
  const ushort_t* vt = wsV + ((size_t)u << 12);
  const int nk = (w >> 1) + 1;

  short8 mfr[4][2];
#pragma unroll
  for (int j = 0; j < 4; ++j)
#pragma unroll
    for (int kk = 0; kk < 2; ++kk)
      mfr[j][kk] = *(const short8*)(mm + (16 * j + r16) * 64 + kk * 32 + 8 * g);

  short8 vfr[4][2];
#pragma unroll
  for (int kk = 0; kk < 2; ++kk)
#pragma unroll
    for (int j = 0; j < 4; ++j) {
      if (kk < nk)
        vfr[j][kk] = *(const short8*)(vt + swz(16 * j + r16, kk * 32 + 8 * g));
      else
        vfr[j][kk] = short8{};
    }

  float4 kraw[4][4];
#pragma unroll
  for (int j = 0; j < 4; ++j) {
    const size_t s = (size_t)(b * Sq + t0 + 16 * j + r16);
    const float4* kp = (const float4*)(qk + ((s * 2 + 1) * Hq + h) * 64);
#pragma unroll
    for (int p2 = 0; p2 < 2; ++p2) {
      if (j <= w) {
        kraw[j][2 * p2]     = kp[8 * p2 + 2 * g];
        kraw[j][2 * p2 + 1] = kp[8 * p2 + 2 * g + 1];
      } else {
        kraw[j][2 * p2]     = make_float4(0.f, 0.f, 0.f, 0.f);
        kraw[j][2 * p2 + 1] = make_float4(0.f, 0.f, 0.f, 0.f);
      }
    }
  }

  float4 qraw[4];
  {
    const size_t t = (size_t)(b * Sq + t0 + 16 * w + r16);
    const float4* qp = (const float4*)(qk + ((t * 2 + 0) * Hq + h) * 64);
#pragma unroll
    for (int p2 = 0; p2 < 2; ++p2) {
      qraw[2 * p2]     = qp[8 * p2 + 2 * g];
      qraw[2 * p2 + 1] = qp[8 * p2 + 2 * g + 1];
    }
  }

  float gn[4];
#pragma unroll
  for (int reg = 0; reg < 4; ++reg)
    gn[reg] = nrm[((size_t)(b * Sq) + t0 + 16 * w + 4 * g + reg) * Hq + h];

  __builtin_amdgcn_sched_barrier(0);

  short8 qf[2];
#pragma unroll
  for (int kk = 0; kk < 2; ++kk) {
    float4 a = qraw[2 * kk], bb = qraw[2 * kk + 1];
    short8 qv;
    qv[0] = f2b(a.x);  qv[1] = f2b(a.y);  qv[2] = f2b(a.z);  qv[3] = f2b(a.w);
    qv[4] = f2b(bb.x); qv[5] = f2b(bb.y); qv[6] = f2b(bb.z); qv[7] = f2b(bb.w);
    qf[kk] = qv;
  }

#pragma unroll
  for (int j = 0; j < 4; ++j) {
    f32x4 acc = {0.f, 0.f, 0.f, 0.f};
#pragma unroll
    for (int kk = 0; kk < 2; ++kk) {
      float4 a = kraw[j][2 * kk], bb = kraw[j][2 * kk + 1];
      short8 kf;
      kf[0] = f2b(a.x);  kf[1] = f2b(a.y);  kf[2] = f2b(a.z);  kf[3] = f2b(a.w);
      kf[4] = f2b(bb.x); kf[5] = f2b(bb.y); kf[6] = f2b(bb.z); kf[7] = f2b(bb.w);
      acc = __builtin_amdgcn_mfma_f32_16x16x32_bf16(qf[kk], kf, acc, 0, 0, 0);
    }
    const int scol = 16 * j + r16;
#pragma unroll
    for (int reg = 0; reg < 4; ++reg) {
      const int trow = 16 * w + 4 * g + reg;
      smS[swz(trow, scol)] = (scol <= trow) ? f2b(acc[reg]) : (short)0;
    }
  }
  asm volatile("s_waitcnt lgkmcnt(0)" ::: "memory");
  __builtin_amdgcn_sched_barrier(0);

  short8 sf0 = *(const short8*)&smS[swz(16 * w + r16, 8 * g)];
  short8 sf1 = short8{};
  if (nk > 1)
    sf1 = *(const short8*)&smS[swz(16 * w + r16, 32 + 8 * g)];

  float gr[4];
#pragma unroll
  for (int reg = 0; reg < 4; ++reg) gr[reg] = __expf(-gn[reg]);

#pragma unroll
  for (int j = 0; j < 4; ++j) {
    f32x4 acc = {0.f, 0.f, 0.f, 0.f};
    acc = __builtin_amdgcn_mfma_f32_16x16x32_bf16(sf0, vfr[j][0], acc, 0, 0, 0);
    acc = __builtin_amdgcn_mfma_f32_16x16x32_bf16(sf1, vfr[j][1], acc, 0, 0, 0);
    acc = __builtin_amdgcn_mfma_f32_16x16x32_bf16(qf[0], mfr[j][0], acc, 0, 0, 0);
    acc = __builtin_amdgcn_mfma_f32_16x16x32_bf16(qf[1], mfr[j][1], acc, 0, 0, 0);
    const int dvv = 16 * j + r16;
#pragma unroll
    for (int reg = 0; reg < 4; ++reg) {
      const int trow = 16 * w + 4 * g + reg;
      out[((size_t)(b * Sq + t0 + trow) * Hq + h) * 64 + dvv] = gr[reg] * acc[reg];
    }
  }
}

extern "C" void kernel_launch(void* const* d_in, const int* in_sizes, int n_in,
                              void* d_out, int out_size, void* d_ws, size_t ws_size,
                              hipStream_t stream) {
  const float* qk = (const float*)d_in[0];
  const float* v  = (const float*)d_in[1];
  const float* nn = (const float*)d_in[2];
  float* out = (float*)d_out;
  ushort_t* wsM = (ushort_t*)d_ws;                 // 8.39MB (coop uses only this)
  ushort_t* wsV = wsM + ((size_t)1024 << 12);      // +8.39MB (fallback only)

  // Deterministic, capture-safe gating: only launch cooperatively if the
  // driver guarantees all 256 blocks co-resident with 2x headroom.
  bool done = false;
  int dev = 0;
  if (hipGetDevice(&dev) == hipSuccess) {
    int coop = 0, ncu = 0, maxb = 0;
    hipError_t e1 =
        hipDeviceGetAttribute(&coop, hipDeviceAttributeCooperativeLaunch, dev);
    hipError_t e2 = hipDeviceGetAttribute(
        &ncu, hipDeviceAttributeMultiprocessorCount, dev);
    if (e1 == hipSuccess && e2 == hipSuccess && coop && ncu > 0 &&
        hipOccupancyMaxActiveBlocksPerMultiprocessor(
            &maxb, (const void*)fused_attn_kernel, 256, 0) == hipSuccess &&
        (long)maxb * ncu >= 2L * 256) {
      void* args[] = {(void*)&qk, (void*)&v, (void*)&nn, (void*)&wsM,
                      (void*)&out};
      done = hipLaunchCooperativeKernel((const void*)fused_attn_kernel,
                                        dim3(256), dim3(256), args, 0,
                                        stream) == hipSuccess;
    }
  }
  if (!done) {   // round-6-verified path
    kv_chunk_kernel<<<1024, 256, 0, stream>>>(qk, v, wsM, wsV);
    kv_scan_kernel<<<256, 256, 0, stream>>>((uint_t*)wsM);
    attn_out_kernel<<<1024, 256, 0, stream>>>(qk, nn, wsM, wsV, out);
  }
}